// Round 7
// baseline (357.729 us; speedup 1.0000x reference)
//
#include <hip/hip_runtime.h>
#include <hip/hip_bf16.h>
#include <math.h>

#define BSZ 4
#define NSEQ 2048
#define CDIM 1024
#define NH 16
#define DH 64
#define KC 64
#define KMAX_STRIDE 32   // one kmax slot per 128B cacheline

typedef _Float16 half8_t __attribute__((ext_vector_type(8)));
typedef _Float16 half4_t __attribute__((ext_vector_type(4)));
typedef _Float16 half2_t __attribute__((ext_vector_type(2)));
typedef float floatx4 __attribute__((ext_vector_type(4)));

#define GLOBAL_AS(p) ((const __attribute__((address_space(1))) void*)(p))
#define LDS_AS(p)    ((__attribute__((address_space(3))) void*)(p))

// Barrier with lgkmcnt(0)-only drain: LDS ordering is preserved but global
// prefetch loads stay in flight (vmcnt NOT drained, unlike __syncthreads).
// imm 0xC07F: vmcnt=max, expcnt=max, lgkmcnt=0 (gfx9-family encoding).
#define BAR_LGKM() do { asm volatile("" ::: "memory");      \
    __builtin_amdgcn_s_waitcnt(0xC07F);                     \
    __builtin_amdgcn_s_barrier();                           \
    asm volatile("" ::: "memory"); } while (0)

// cvt_pkrtz returns __fp16x2; bit-cast to our _Float16x2 (same layout).
static __device__ inline half2_t pkrtz(float a, float b) {
  return __builtin_bit_cast(half2_t, __builtin_amdgcn_cvt_pkrtz(a, b));
}

// ---------------------------------------------------------------------------
// Prep: fp32 -> fp16 casts (weights transposed to [N][K]); block 0 also
// zero-inits the kmax atomic slots (runs before qkv_gemm on the stream).
// ---------------------------------------------------------------------------
__global__ __launch_bounds__(256) void cast_x_kernel(
    const float* __restrict__ src, _Float16* __restrict__ dst,
    unsigned* __restrict__ kmx) {
  if (blockIdx.x == 0) {
    for (int i = threadIdx.x; i < 64 * KMAX_STRIDE; i += 256) kmx[i] = 0u;
  }
  const size_t i = ((size_t)blockIdx.x * 256 + threadIdx.x) * 8;
  float4 a = *(const float4*)(src + i);
  float4 b = *(const float4*)(src + i + 4);
  half8_t h;
  h[0] = (_Float16)a.x; h[1] = (_Float16)a.y; h[2] = (_Float16)a.z; h[3] = (_Float16)a.w;
  h[4] = (_Float16)b.x; h[5] = (_Float16)b.y; h[6] = (_Float16)b.z; h[7] = (_Float16)b.w;
  *(half8_t*)(dst + i) = h;
}

__global__ __launch_bounds__(256) void transpose_cast_kernel(
    const float* __restrict__ src, _Float16* __restrict__ dst, int R, int C) {
  __shared__ float Ls[64][65];
  const int t = threadIdx.x;
  const int r0 = blockIdx.y * 64, c0 = blockIdx.x * 64;
  {
    const int lr = t >> 2, lcg = (t & 3) * 16;
    const float* s = src + (size_t)(r0 + lr) * C + c0 + lcg;
#pragma unroll
    for (int u = 0; u < 4; ++u)
      *(float4*)&Ls[lr][lcg + 4 * u] = *(const float4*)(s + 4 * u);
  }
  __syncthreads();
  const int c = t >> 2, rg = (t & 3) * 16;
  half8_t h0, h1;
#pragma unroll
  for (int u = 0; u < 8; ++u) h0[u] = (_Float16)Ls[rg + u][c];
#pragma unroll
  for (int u = 0; u < 8; ++u) h1[u] = (_Float16)Ls[rg + 8 + u][c];
  _Float16* d = dst + (size_t)(c0 + c) * R + r0 + rg;
  *(half8_t*)d = h0;
  *(half8_t*)(d + 8) = h1;
}

// ---------------------------------------------------------------------------
// Kernel 1: QKV GEMM (fp16 MFMA) + bias + RoPE epilogue + FUSED norm
// computation: qn[bh][n] = ||q row|| (from stored fp16 -> exact C-S bound),
// kmax[bh] = max ||k row|| via one atomicMax per K-wave.
// ---------------------------------------------------------------------------
__global__ __launch_bounds__(256) void qkv_gemm_kernel(
    const _Float16* __restrict__ xh, const _Float16* __restrict__ Wt,
    const float* __restrict__ bias, _Float16* __restrict__ Qh,
    _Float16* __restrict__ Kh, _Float16* __restrict__ Vh,
    float* __restrict__ qn, unsigned* __restrict__ kmx) {
  __shared__ _Float16 As[128 * 64];
  __shared__ _Float16 Bs[128 * 64];
  const int tid = threadIdx.x;
  const int lane = tid & 63, w = tid >> 6;
  const int m = lane & 15, quad = lane >> 4;
  const int wr = (w >> 1) * 64, wc = (w & 1) * 64;
  const int m0 = blockIdx.y * 128;
  const int N0 = blockIdx.x * 128;
  const int sr = lane >> 3, sc = (lane & 7) * 8;

  floatx4 acc[4][4];
#pragma unroll
  for (int i = 0; i < 4; ++i)
#pragma unroll
    for (int j = 0; j < 4; ++j) acc[i][j] = (floatx4){0.f, 0.f, 0.f, 0.f};

  for (int k0 = 0; k0 < CDIM; k0 += 64) {
    __syncthreads();
#pragma unroll
    for (int i = 0; i < 4; ++i) {
      const int row = (w * 4 + i) * 8 + sr;
      __builtin_amdgcn_global_load_lds(
          GLOBAL_AS(xh + (size_t)(m0 + row) * CDIM + k0 + sc),
          LDS_AS(As + (w * 4 + i) * 512), 16, 0, 0);
      __builtin_amdgcn_global_load_lds(
          GLOBAL_AS(Wt + (size_t)(N0 + row) * CDIM + k0 + sc),
          LDS_AS(Bs + (w * 4 + i) * 512), 16, 0, 0);
    }
    __syncthreads();
#pragma unroll
    for (int ks = 0; ks < 2; ++ks) {
      half8_t af[4], bf[4];
#pragma unroll
      for (int mt = 0; mt < 4; ++mt)
        af[mt] = *(half8_t*)(As + (wr + mt * 16 + m) * 64 + ks * 32 + quad * 8);
#pragma unroll
      for (int nt = 0; nt < 4; ++nt)
        bf[nt] = *(half8_t*)(Bs + (wc + nt * 16 + m) * 64 + ks * 32 + quad * 8);
#pragma unroll
      for (int mt = 0; mt < 4; ++mt)
#pragma unroll
        for (int nt = 0; nt < 4; ++nt)
          acc[mt][nt] = __builtin_amdgcn_mfma_f32_16x16x32_f16(
              af[mt], bf[nt], acc[mt][nt], 0, 0, 0);
    }
  }

  const int F0 = N0 + wc;
  const int which = F0 >> 10;
  const int head = (F0 & 1023) >> 6;
  float bv[4];
#pragma unroll
  for (int nt = 0; nt < 4; ++nt) bv[nt] = bias[F0 + nt * 16 + m];

  if (which == 2) {
#pragma unroll
    for (int mt = 0; mt < 4; ++mt)
#pragma unroll
      for (int reg = 0; reg < 4; ++reg) {
        const int gm = m0 + wr + mt * 16 + 4 * quad + reg;
        const int b = gm >> 11, n = gm & 2047;
        const size_t vbase = ((size_t)(b * NH + head) * DH) * NSEQ + n;
#pragma unroll
        for (int nt = 0; nt < 4; ++nt)
          Vh[vbase + (size_t)(nt * 16 + m) * NSEQ] =
              (_Float16)(acc[mt][nt][reg] + bv[nt]);
      }
  } else {
    _Float16* dst = which ? Kh : Qh;
    const float qs = which ? 1.0f : 0.125f * 1.4426950408889634f;
    const float invfA = expf(-9.210340371976184f * ((float)m * (1.0f / 32.0f)));
    const float invfB = expf(-9.210340371976184f * ((float)(16 + m) * (1.0f / 32.0f)));
    float kms = 0.f;
#pragma unroll
    for (int mt = 0; mt < 4; ++mt)
#pragma unroll
      for (int reg = 0; reg < 4; ++reg) {
        const int gm = m0 + wr + mt * 16 + 4 * quad + reg;
        const int b = gm >> 11, n = gm & 2047;
        float sA, cA, sB, cB;
        sincosf((float)n * invfA, &sA, &cA);
        sincosf((float)n * invfB, &sB, &cB);
        const size_t obase = ((size_t)(b * NH + head) * NSEQ + n) * DH;
        float s2 = 0.f;
#pragma unroll
        for (int nt = 0; nt < 4; ++nt) {
          const float val = acc[mt][nt][reg] + bv[nt];
          const float rot = (nt < 2) ? -(acc[mt][nt + 2][reg] + bv[nt + 2])
                                     :  (acc[mt][nt - 2][reg] + bv[nt - 2]);
          const float sv = (nt & 1) ? sB : sA;
          const float cv = (nt & 1) ? cB : cA;
          const _Float16 h = (_Float16)((val * cv + rot * sv) * qs);
          dst[obase + nt * 16 + m] = h;
          const float f = (float)h;
          s2 += f * f;
        }
        // reduce over the 16 m-lanes of this quad (row = 4*quad+reg)
        s2 += __shfl_xor(s2, 1, 64);
        s2 += __shfl_xor(s2, 2, 64);
        s2 += __shfl_xor(s2, 4, 64);
        s2 += __shfl_xor(s2, 8, 64);
        if (which == 0) {
          if (m == 0) qn[((size_t)(b * NH + head)) * NSEQ + n] = sqrtf(s2);
        } else {
          kms = fmaxf(kms, s2);
        }
      }
    if (which == 1) {
      kms = fmaxf(kms, __shfl_xor(kms, 16, 64));
      kms = fmaxf(kms, __shfl_xor(kms, 32, 64));
      if (lane == 0) {
        const int b = (m0 + wr) >> 11;
        atomicMax(&kmx[(b * NH + head) * KMAX_STRIDE],
                  __float_as_uint(sqrtf(kms)));
      }
    }
  }
}

// ---------------------------------------------------------------------------
// Kernel 2: flash attention, fixed C-S max, SOFTWARE-PIPELINED staging:
// chunk ck+1's K/V prefetched into registers during chunk ck's compute;
// loop barriers drain lgkmcnt only (global prefetch stays in flight).
// l computed via mfma(P, ones) -- no per-element adds, no end shuffles.
// ---------------------------------------------------------------------------
__global__ __launch_bounds__(256) void attn_kernel(
    const _Float16* __restrict__ Qh, const _Float16* __restrict__ Kh,
    const _Float16* __restrict__ Vh, const float* __restrict__ qn,
    const unsigned* __restrict__ kmaxu, _Float16* __restrict__ AO) {
  __shared__ char smem[36864];
  _Float16* Ks = (_Float16*)smem;            // [64][72]
  _Float16* Vt = (_Float16*)(smem + 9216);   // [64][72] (rows = d)
  _Float16* Ps = (_Float16*)(smem + 18432);  // [4 waves][32 q][72]
  float* Os = (float*)smem;                  // [128][68] epilogue reuse

  const int tid = threadIdx.x;
  const int lane = tid & 63;
  const int w = tid >> 6;
  const int m = lane & 15;
  const int quad = lane >> 4;
  const int bh = blockIdx.y;
  const int q0 = blockIdx.x * 128;

  const _Float16* Qb = Qh + (size_t)bh * NSEQ * DH;
  const _Float16* Kb = Kh + (size_t)bh * NSEQ * DH;
  const _Float16* Vb = Vh + (size_t)bh * DH * NSEQ;

  const int rA = q0 + w * 32 + m;
  const int rB = rA + 16;
  half8_t qfA0 = *(const half8_t*)(Qb + (size_t)rA * DH + quad * 8);
  half8_t qfA1 = *(const half8_t*)(Qb + (size_t)rA * DH + 32 + quad * 8);
  half8_t qfB0 = *(const half8_t*)(Qb + (size_t)rB * DH + quad * 8);
  half8_t qfB1 = *(const half8_t*)(Qb + (size_t)rB * DH + 32 + quad * 8);

  const float kmx = __uint_as_float(kmaxu[bh * KMAX_STRIDE]);
  const float mA = qn[(size_t)bh * NSEQ + rA] * kmx;
  const float mB = qn[(size_t)bh * NSEQ + rB] * kmx;

  half8_t ones;
#pragma unroll
  for (int u = 0; u < 8; ++u) ones[u] = (_Float16)1.0f;

  floatx4 OA[4], OB[4], OLA, OLB;
#pragma unroll
  for (int nb = 0; nb < 4; ++nb) {
    OA[nb] = (floatx4){0.f, 0.f, 0.f, 0.f};
    OB[nb] = (floatx4){0.f, 0.f, 0.f, 0.f};
  }
  OLA = (floatx4){0.f, 0.f, 0.f, 0.f};
  OLB = (floatx4){0.f, 0.f, 0.f, 0.f};

  _Float16* PwA = Ps + w * 2304 + m * 72;
  _Float16* PwB = PwA + 16 * 72;

  const int skey0 = tid >> 3, skey1 = skey0 + 32, sdg = (tid & 7) * 8;

  auto stage_load = [&](int cki, half8_t& k0r, half8_t& k1r,
                        half8_t& v0r, half8_t& v1r) {
    const _Float16* Kc = Kb + (size_t)cki * KC * DH;
    const _Float16* Vc = Vb + cki * KC;
    k0r = *(const half8_t*)(Kc + skey0 * 64 + sdg);
    k1r = *(const half8_t*)(Kc + skey1 * 64 + sdg);
    v0r = *(const half8_t*)(Vc + (size_t)skey0 * NSEQ + sdg);
    v1r = *(const half8_t*)(Vc + (size_t)skey1 * NSEQ + sdg);
  };
  auto stage_store = [&](half8_t k0r, half8_t k1r, half8_t v0r, half8_t v1r) {
    *(half8_t*)(Ks + skey0 * 72 + sdg) = k0r;
    *(half8_t*)(Ks + skey1 * 72 + sdg) = k1r;
    *(half8_t*)(Vt + skey0 * 72 + sdg) = v0r;
    *(half8_t*)(Vt + skey1 * 72 + sdg) = v1r;
  };
  auto compute_chunk = [&]() {
    floatx4 stA[4], stB[4];
#pragma unroll
    for (int kt = 0; kt < 4; ++kt) {
      half8_t kf0 = *(half8_t*)(Ks + (kt * 16 + m) * 72 + quad * 8);
      half8_t kf1 = *(half8_t*)(Ks + (kt * 16 + m) * 72 + 32 + quad * 8);
      floatx4 a = (floatx4){0.f, 0.f, 0.f, 0.f};
      a = __builtin_amdgcn_mfma_f32_16x16x32_f16(kf0, qfA0, a, 0, 0, 0);
      a = __builtin_amdgcn_mfma_f32_16x16x32_f16(kf1, qfA1, a, 0, 0, 0);
      stA[kt] = a;
      floatx4 b = (floatx4){0.f, 0.f, 0.f, 0.f};
      b = __builtin_amdgcn_mfma_f32_16x16x32_f16(kf0, qfB0, b, 0, 0, 0);
      b = __builtin_amdgcn_mfma_f32_16x16x32_f16(kf1, qfB1, b, 0, 0, 0);
      stB[kt] = b;
    }
#pragma unroll
    for (int kt = 0; kt < 4; ++kt) {
      half2_t a01 = pkrtz(__builtin_exp2f(stA[kt][0] - mA),
                          __builtin_exp2f(stA[kt][1] - mA));
      half2_t a23 = pkrtz(__builtin_exp2f(stA[kt][2] - mA),
                          __builtin_exp2f(stA[kt][3] - mA));
      half2_t b01 = pkrtz(__builtin_exp2f(stB[kt][0] - mB),
                          __builtin_exp2f(stB[kt][1] - mB));
      half2_t b23 = pkrtz(__builtin_exp2f(stB[kt][2] - mB),
                          __builtin_exp2f(stB[kt][3] - mB));
      *(half4_t*)(PwA + kt * 16 + quad * 4) =
          __builtin_shufflevector(a01, a23, 0, 1, 2, 3);
      *(half4_t*)(PwB + kt * 16 + quad * 4) =
          __builtin_shufflevector(b01, b23, 0, 1, 2, 3);
    }
#pragma unroll
    for (int c = 0; c < 2; ++c) {
      half8_t pfA = *(half8_t*)(PwA + c * 32 + quad * 8);
      half8_t pfB = *(half8_t*)(PwB + c * 32 + quad * 8);
      OLA = __builtin_amdgcn_mfma_f32_16x16x32_f16(pfA, ones, OLA, 0, 0, 0);
      OLB = __builtin_amdgcn_mfma_f32_16x16x32_f16(pfB, ones, OLB, 0, 0, 0);
#pragma unroll
      for (int nb = 0; nb < 4; ++nb) {
        half8_t vf = *(half8_t*)(Vt + (nb * 16 + m) * 72 + c * 32 + quad * 8);
        OA[nb] = __builtin_amdgcn_mfma_f32_16x16x32_f16(pfA, vf, OA[nb], 0, 0, 0);
        OB[nb] = __builtin_amdgcn_mfma_f32_16x16x32_f16(pfB, vf, OB[nb], 0, 0, 0);
      }
    }
  };

  half8_t ka0, ka1, va0, va1, kb0, kb1, vb0, vb1;
  stage_load(0, ka0, ka1, va0, va1);
  for (int ck = 0; ck < NSEQ / KC; ck += 2) {
    BAR_LGKM();                                  // prior compute's LDS reads done
    stage_load(ck + 1, kb0, kb1, vb0, vb1);      // prefetch next (always valid)
    stage_store(ka0, ka1, va0, va1);
    BAR_LGKM();                                  // ds_writes visible; vm in flight
    compute_chunk();
    BAR_LGKM();
    if (ck + 2 < NSEQ / KC) stage_load(ck + 2, ka0, ka1, va0, va1);
    stage_store(kb0, kb1, vb0, vb1);
    BAR_LGKM();
    compute_chunk();
  }

  // epilogue: l lives in OLA/OLB C-layout rows (every col identical)
  float invA[4], invB[4];
#pragma unroll
  for (int r = 0; r < 4; ++r) {
    invA[r] = 1.0f / OLA[r];
    invB[r] = 1.0f / OLB[r];
  }
  __syncthreads();
#pragma unroll
  for (int nb = 0; nb < 4; ++nb) {
#pragma unroll
    for (int r = 0; r < 4; ++r) {
      Os[(w * 32 + 4 * quad + r) * 68 + nb * 16 + m] = OA[nb][r] * invA[r];
      Os[(w * 32 + 16 + 4 * quad + r) * 68 + nb * 16 + m] = OB[nb][r] * invB[r];
    }
  }
  __syncthreads();
  const int ql = tid >> 1, dg = (tid & 1) * 32;
  const int b = bh >> 4, h = bh & 15;
  _Float16* dst = AO + ((size_t)(b * NSEQ + q0 + ql)) * CDIM + h * DH + dg;
#pragma unroll
  for (int u = 0; u < 4; ++u) {
    half8_t o;
#pragma unroll
    for (int v = 0; v < 8; ++v) o[v] = (_Float16)Os[ql * 68 + dg + u * 8 + v];
    *(half8_t*)(dst + u * 8) = o;
  }
}

// ---------------------------------------------------------------------------
// Kernel 3: proj GEMM (fp16 MFMA) + bias, fp32 out (unchanged).
// ---------------------------------------------------------------------------
__global__ __launch_bounds__(256) void proj_gemm_kernel(
    const _Float16* __restrict__ Ah, const _Float16* __restrict__ Wt,
    const float* __restrict__ bias, float* __restrict__ out) {
  __shared__ _Float16 As[128 * 64];
  __shared__ _Float16 Bs[128 * 64];
  const int tid = threadIdx.x;
  const int lane = tid & 63, w = tid >> 6;
  const int m = lane & 15, quad = lane >> 4;
  const int wr = (w >> 1) * 64, wc = (w & 1) * 64;
  const int m0 = blockIdx.y * 128;
  const int N0 = blockIdx.x * 128;
  const int sr = lane >> 3, sc = (lane & 7) * 8;

  floatx4 acc[4][4];
#pragma unroll
  for (int i = 0; i < 4; ++i)
#pragma unroll
    for (int j = 0; j < 4; ++j) acc[i][j] = (floatx4){0.f, 0.f, 0.f, 0.f};

  for (int k0 = 0; k0 < CDIM; k0 += 64) {
    __syncthreads();
#pragma unroll
    for (int i = 0; i < 4; ++i) {
      const int row = (w * 4 + i) * 8 + sr;
      __builtin_amdgcn_global_load_lds(
          GLOBAL_AS(Ah + (size_t)(m0 + row) * CDIM + k0 + sc),
          LDS_AS(As + (w * 4 + i) * 512), 16, 0, 0);
      __builtin_amdgcn_global_load_lds(
          GLOBAL_AS(Wt + (size_t)(N0 + row) * CDIM + k0 + sc),
          LDS_AS(Bs + (w * 4 + i) * 512), 16, 0, 0);
    }
    __syncthreads();
#pragma unroll
    for (int ks = 0; ks < 2; ++ks) {
      half8_t af[4], bf[4];
#pragma unroll
      for (int mt = 0; mt < 4; ++mt)
        af[mt] = *(half8_t*)(As + (wr + mt * 16 + m) * 64 + ks * 32 + quad * 8);
#pragma unroll
      for (int nt = 0; nt < 4; ++nt)
        bf[nt] = *(half8_t*)(Bs + (wc + nt * 16 + m) * 64 + ks * 32 + quad * 8);
#pragma unroll
      for (int mt = 0; mt < 4; ++mt)
#pragma unroll
        for (int nt = 0; nt < 4; ++nt)
          acc[mt][nt] = __builtin_amdgcn_mfma_f32_16x16x32_f16(
              af[mt], bf[nt], acc[mt][nt], 0, 0, 0);
    }
  }

  const int F0 = N0 + wc;
  float bv[4];
#pragma unroll
  for (int nt = 0; nt < 4; ++nt) bv[nt] = bias[F0 + nt * 16 + m];
#pragma unroll
  for (int mt = 0; mt < 4; ++mt)
#pragma unroll
    for (int reg = 0; reg < 4; ++reg) {
      const int gm = m0 + wr + mt * 16 + 4 * quad + reg;
#pragma unroll
      for (int nt = 0; nt < 4; ++nt)
        out[(size_t)gm * CDIM + F0 + nt * 16 + m] = acc[mt][nt][reg] + bv[nt];
    }
}

// ---------------------------------------------------------------------------
extern "C" void kernel_launch(void* const* d_in, const int* in_sizes, int n_in,
                              void* d_out, int out_size, void* d_ws, size_t ws_size,
                              hipStream_t stream) {
  const float* x     = (const float*)d_in[0];
  const float* Wqkv  = (const float*)d_in[1];
  const float* bqkv  = (const float*)d_in[2];
  const float* Wproj = (const float*)d_in[3];
  const float* bproj = (const float*)d_in[4];
  float* out = (float*)d_out;

  const size_t per = (size_t)BSZ * NH * NSEQ * DH;  // 8,388,608
  _Float16* xh  = (_Float16*)d_ws;
  _Float16* Wt  = xh + per;                 // [3072][1024]
  _Float16* Wpt = Wt + (size_t)3072 * 1024; // [1024][1024]
  _Float16* Qh  = Wpt + (size_t)1024 * 1024;
  _Float16* Kh  = Qh + per;
  _Float16* Vh  = Kh + per;
  _Float16* AOh = Vh + per;
  float*    qnp = (float*)(AOh + per);      // [64*2048] q-row norms
  unsigned* kmx = (unsigned*)(qnp + (size_t)64 * NSEQ);  // [64*KMAX_STRIDE]

  cast_x_kernel<<<4096, 256, 0, stream>>>(x, xh, kmx);
  transpose_cast_kernel<<<dim3(48, 16), 256, 0, stream>>>(Wqkv, Wt, 1024, 3072);
  transpose_cast_kernel<<<dim3(16, 16), 256, 0, stream>>>(Wproj, Wpt, 1024, 1024);
  qkv_gemm_kernel<<<dim3(24, 64), 256, 0, stream>>>(xh, Wt, bqkv, Qh, Kh, Vh,
                                                    qnp, kmx);
  attn_kernel<<<dim3(16, 64), 256, 0, stream>>>(Qh, Kh, Vh, qnp, kmx, AOh);
  proj_gemm_kernel<<<dim3(8, 64), 256, 0, stream>>>(AOh, Wpt, bproj, out);
}